// Round 1
// baseline (427.991 us; speedup 1.0000x reference)
//
#include <hip/hip_runtime.h>

// Problem constants (fixed by the reference): B=8, S=512, D=384, VOCAB=50257.
#define BB 8
#define SS 512
#define DD 384
#define K2 (DD * DD)          // 147456 = flattened (d,e)
#define LCH 16                // list entries processed per pass (LDS-resident)
#define OT 4                  // output-o's per thread tile
#define KCH 8                 // k-chunks (grid.y)
#define GROUPS (K2 / 4)       // 36864 float4-groups over k
#define GPC (GROUPS / KCH)    // 4608 groups per chunk
#define NTHREADS 256
#define MAXL_CAP 4096

// ws layout: [0..16) count (int), [16..16400) list (4096 ints), [16400..) u buffer
#define WS_LIST_OFF 16
#define WS_U_OFF 16400

// ---------------------------------------------------------------------------
// Kernel 1: flag positions s2 whose head s1 satisfies heads[b,s1]==0.
// Only those s2 need the expensive bilinear u[b,s2,:].
__global__ void flag_kernel(const int* __restrict__ heads, int* __restrict__ countp,
                            int* __restrict__ list, int maxl) {
    int b = blockIdx.x;
    int s2 = threadIdx.x;
    int h = heads[b * SS + s2];
    if (heads[b * SS + h] == 0) {
        int idx = atomicAdd(countp, 1);
        if (idx < maxl) list[idx] = b * SS + s2;
    }
}

// ---------------------------------------------------------------------------
// Kernel 2: u[l,o] = sum_k p[l,k] * Wc[o,k], k = d*384+e, p = tok[l,d]*dep[l,e].
// Streams Wc exactly once (226 MB) with coalesced float4 loads; tok/dep rows
// for up to LCH list entries live in LDS; register accumulators; wave-shuffle
// reduce + atomicAdd(f32) into u.
__global__ __launch_bounds__(NTHREADS) void bilinear_kernel(
    const float* __restrict__ Wc, const float* __restrict__ tok_table,
    const int* __restrict__ tokens, const int* __restrict__ list,
    const int* __restrict__ countp, float* __restrict__ u, int maxl) {
    __shared__ alignas(16) float tokS[LCH][DD];
    __shared__ alignas(16) float depS[LCH][DD];

    const int tid = threadIdx.x;
    const int o0 = blockIdx.x * OT;          // o tile base, 96 groups
    const int g0 = blockIdx.y * GPC;         // k-chunk base (in float4 groups)

    int total = *countp;
    if (total > maxl) total = maxl;

    for (int cb = 0; cb < total; cb += LCH) {
        // ---- stage tok/dep rows for this list-chunk into LDS (zero-padded)
        for (int idx = tid; idx < LCH * DD; idx += NTHREADS) {
            int l = idx / DD;
            int i = idx - l * DD;
            float t = 0.f;
            if (cb + l < total) {
                int pos = list[cb + l];
                t = tok_table[(size_t)tokens[pos] * DD + i];
            }
            tokS[l][i] = t;
            depS[l][i] = tanhf(t);           // t==0 -> dep==0 -> contributes 0
        }
        __syncthreads();

        float acc[LCH][OT];
#pragma unroll
        for (int l = 0; l < LCH; ++l)
#pragma unroll
            for (int j = 0; j < OT; ++j) acc[l][j] = 0.f;

        // ---- main stream over Wc: 18 iterations of 256 float4-groups
#pragma unroll 1
        for (int it = 0; it < GPC / NTHREADS; ++it) {
            int g = g0 + it * NTHREADS + tid;     // float4-group index
            int d = g / 96;                       // 4 divides 384: d uniform in group
            int e4 = g - d * 96;                  // float4 index within dep row

            float4 wv[OT];
#pragma unroll
            for (int j = 0; j < OT; ++j)
                wv[j] = *(const float4*)(Wc + (size_t)(o0 + j) * K2 + 4 * (size_t)g);

#pragma unroll
            for (int l = 0; l < LCH; ++l) {
                float td = tokS[l][d];
                float4 dv = *(const float4*)(&depS[l][e4 * 4]);
                float px = td * dv.x, py = td * dv.y, pz = td * dv.z, pw = td * dv.w;
#pragma unroll
                for (int j = 0; j < OT; ++j)
                    acc[l][j] += px * wv[j].x + py * wv[j].y + pz * wv[j].z + pw * wv[j].w;
            }
        }

        // ---- reduce across wave, atomicAdd partials into u
        int lane = tid & 63;
#pragma unroll
        for (int l = 0; l < LCH; ++l) {
            if (cb + l < total) {
#pragma unroll
                for (int j = 0; j < OT; ++j) {
                    float v = acc[l][j];
                    for (int off = 32; off > 0; off >>= 1) v += __shfl_down(v, off, 64);
                    if (lane == 0)
                        atomicAdd(&u[(size_t)(cb + l) * DD + o0 + j], v);
                }
            }
        }
        __syncthreads();  // protect LDS before next chunk's staging
    }
}

// ---------------------------------------------------------------------------
// Kernel 3: output. Rows with heads!=0 -> zeros. Rows with heads==0 ->
// base[o] + sum over list entries whose head == this row of
// (tanh(u+bc)-tanh(bc)) * Wr[s2].
__global__ __launch_bounds__(128) void finalize_kernel(
    const int* __restrict__ heads, const float* __restrict__ Wr,
    const float* __restrict__ bc, const float* __restrict__ br,
    const int* __restrict__ list, const int* __restrict__ countp,
    const float* __restrict__ u, float* __restrict__ out, int maxl) {
    int row = blockIdx.x;
    int tid = threadIdx.x;
    bool nz = (heads[row] == 0);
    if (!nz) {
        for (int o = tid; o < DD; o += 128) out[(size_t)row * DD + o] = 0.f;
        return;
    }
    int b = row >> 9;     // /512
    int s1 = row & 511;

    float sumw = 0.f;
    for (int s = 0; s < SS; ++s) sumw += Wr[s];
    float brv = br[0];

    int total = *countp;
    if (total > maxl) total = maxl;

    for (int o = tid; o < DD; o += 128) {
        float bco = bc[o];
        float t_off = tanhf(bco);
        float val = t_off * sumw + brv;
        for (int l = 0; l < total; ++l) {
            int pos = list[l];
            if ((pos >> 9) == b && heads[pos] == s1) {
                val += (tanhf(u[(size_t)l * DD + o] + bco) - t_off) * Wr[pos & 511];
            }
        }
        out[(size_t)row * DD + o] = val;
    }
}

// ---------------------------------------------------------------------------
extern "C" void kernel_launch(void* const* d_in, const int* in_sizes, int n_in,
                              void* d_out, int out_size, void* d_ws, size_t ws_size,
                              hipStream_t stream) {
    const int* tokens = (const int*)d_in[0];
    // d_in[1] = dep_types: computed-but-discarded in the reference (bug preserved)
    const int* heads = (const int*)d_in[2];
    const float* tok_table = (const float*)d_in[3];
    const float* Wc = (const float*)d_in[4];
    const float* bc = (const float*)d_in[5];
    const float* Wr = (const float*)d_in[6];
    const float* br = (const float*)d_in[7];
    float* out = (float*)d_out;

    char* ws = (char*)d_ws;
    int* countp = (int*)ws;
    int* list = (int*)(ws + WS_LIST_OFF);
    float* u = (float*)(ws + WS_U_OFF);

    long maxl_l = ((long)ws_size - WS_U_OFF) / (DD * 4);
    int maxl = maxl_l < 0 ? 0 : (maxl_l > MAXL_CAP ? MAXL_CAP : (int)maxl_l);

    // zero count + list + u scratch (harness poisons ws with 0xAA every call)
    hipMemsetAsync(d_ws, 0, (size_t)WS_U_OFF + (size_t)maxl * DD * 4, stream);

    flag_kernel<<<BB, SS, 0, stream>>>(heads, countp, list, maxl);
    bilinear_kernel<<<dim3(DD / OT, KCH), NTHREADS, 0, stream>>>(
        Wc, tok_table, tokens, list, countp, u, maxl);
    finalize_kernel<<<BB * SS, 128, 0, stream>>>(
        heads, Wr, bc, br, list, countp, u, out, maxl);
}

// Round 2
// 392.753 us; speedup vs baseline: 1.0897x; 1.0897x over previous
//
#include <hip/hip_runtime.h>

// Problem constants (fixed by the reference): B=8, S=512, D=384, VOCAB=50257.
#define BB 8
#define SS 512
#define DD 384
#define K2 (DD * DD)          // 147456 = flattened (d,e)
#define LCH 16                // list entries per pass (LDS-resident); FETCH shows total<=16
#define OT 2                  // o-rows per block (acc = LCH*OT = 32 VGPRs)
#define KCH 4                 // k-chunks (grid.y)
#define GROUPS (K2 / 4)       // 36864 float4-groups over k
#define GPC (GROUPS / KCH)    // 9216 groups per chunk
#define NT 512                // 8 waves/block; 3 blocks/CU (LDS) -> 24 waves/CU
#define ITERS (GPC / NT)      // 18
#define MAXL_CAP 1024

// ws layout: [0..16) count (int), [16..16400) list (ints), [16400..) u buffer
#define WS_LIST_OFF 16
#define WS_U_OFF 16400

// ---------------------------------------------------------------------------
// Kernel 1: flag positions s2 whose head s1 satisfies heads[b,s1]==0.
__global__ void flag_kernel(const int* __restrict__ heads, int* __restrict__ countp,
                            int* __restrict__ list, int maxl) {
    int b = blockIdx.x;
    int s2 = threadIdx.x;
    int h = heads[b * SS + s2];
    if (heads[b * SS + h] == 0) {
        int idx = atomicAdd(countp, 1);
        if (idx < maxl) list[idx] = b * SS + s2;
    }
}

// ---------------------------------------------------------------------------
// Kernel 2: u[l,o] = sum_k p[l,k] * Wc[o,k], k = d*384+e, p = tok[l,d]*dep[l,e].
// Streams Wc once, coalesced float4; explicit next-iter prefetch keeps 2 loads
// in flight per thread; 24 waves/CU hide HBM latency.
__global__ __launch_bounds__(NT, 6) void bilinear_kernel(
    const float* __restrict__ Wc, const float* __restrict__ tok_table,
    const int* __restrict__ tokens, const int* __restrict__ list,
    const int* __restrict__ countp, float* __restrict__ u, int maxl) {
    __shared__ alignas(16) float tokS[LCH][DD];
    __shared__ alignas(16) float depS[LCH][DD];

    const int tid = threadIdx.x;
    const int o0 = blockIdx.x * OT;          // 192 o-pairs
    const int g0 = blockIdx.y * GPC;         // k-chunk base (float4 groups)

    int total = *countp;
    if (total > maxl) total = maxl;

    for (int cb = 0; cb < total; cb += LCH) {
        // ---- stage tok/dep rows into LDS (zero-padded)
        for (int idx = tid; idx < LCH * DD; idx += NT) {
            int l = idx / DD;
            int i = idx - l * DD;
            float t = 0.f;
            if (cb + l < total) {
                int pos = list[cb + l];
                t = tok_table[(size_t)tokens[pos] * DD + i];
            }
            tokS[l][i] = t;
            depS[l][i] = tanhf(t);           // t==0 -> dep==0 -> contributes 0
        }
        __syncthreads();

        float acc[LCH][OT];
#pragma unroll
        for (int l = 0; l < LCH; ++l)
#pragma unroll
            for (int j = 0; j < OT; ++j) acc[l][j] = 0.f;

        // ---- prefetch iteration 0
        const float* wbase = Wc + (size_t)o0 * K2;
        float4 wv0, wv1;
        {
            const float* wp = wbase + 4 * (size_t)(g0 + tid);
            wv0 = *(const float4*)wp;
            wv1 = *(const float4*)(wp + K2);
        }

#pragma unroll 1
        for (int it = 0; it < ITERS; ++it) {
            int gc = g0 + it * NT + tid;

            // prefetch next iteration before consuming current
            float4 nv0 = make_float4(0.f, 0.f, 0.f, 0.f), nv1 = nv0;
            if (it + 1 < ITERS) {
                const float* wp = wbase + 4 * (size_t)(gc + NT);
                nv0 = *(const float4*)wp;
                nv1 = *(const float4*)(wp + K2);
            }

            int d = gc / 96;                  // uniform-ish across lanes (<=2 values)
            int e4 = gc - d * 96;             // float4 index within dep row

#pragma unroll
            for (int l = 0; l < LCH; ++l) {
                float td = tokS[l][d];
                float4 dv = *(const float4*)(&depS[l][e4 * 4]);
                float px = td * dv.x, py = td * dv.y, pz = td * dv.z, pw = td * dv.w;
                acc[l][0] += px * wv0.x + py * wv0.y + pz * wv0.z + pw * wv0.w;
                acc[l][1] += px * wv1.x + py * wv1.y + pz * wv1.z + pw * wv1.w;
            }
            wv0 = nv0;
            wv1 = nv1;
        }

        // ---- wave-shuffle reduce, atomicAdd partials into u
        int lane = tid & 63;
#pragma unroll
        for (int l = 0; l < LCH; ++l) {
            if (cb + l < total) {
#pragma unroll
                for (int j = 0; j < OT; ++j) {
                    float v = acc[l][j];
                    for (int off = 32; off > 0; off >>= 1) v += __shfl_down(v, off, 64);
                    if (lane == 0)
                        atomicAdd(&u[(size_t)(cb + l) * DD + o0 + j], v);
                }
            }
        }
        __syncthreads();  // protect LDS before next chunk's staging
    }
}

// ---------------------------------------------------------------------------
// Kernel 3: output. heads!=0 rows -> zeros (float4). heads==0 rows ->
// base[o] + sum over list entries with head==row of (tanh(u+bc)-tanh(bc))*Wr.
__global__ __launch_bounds__(128) void finalize_kernel(
    const int* __restrict__ heads, const float* __restrict__ Wr,
    const float* __restrict__ bc, const float* __restrict__ br,
    const int* __restrict__ list, const int* __restrict__ countp,
    const float* __restrict__ u, float* __restrict__ out, int maxl) {
    int row = blockIdx.x;
    int tid = threadIdx.x;
    if (heads[row] != 0) {
        if (tid < DD / 4) {
            float4 z = make_float4(0.f, 0.f, 0.f, 0.f);
            ((float4*)(out + (size_t)row * DD))[tid] = z;
        }
        return;
    }
    int b = row >> 9;     // /512
    int s1 = row & 511;

    float sumw = 0.f;
    for (int s = 0; s < SS; ++s) sumw += Wr[s];
    float brv = br[0];

    int total = *countp;
    if (total > maxl) total = maxl;

    for (int o = tid; o < DD; o += 128) {
        float bco = bc[o];
        float t_off = tanhf(bco);
        float val = t_off * sumw + brv;
        for (int l = 0; l < total; ++l) {
            int pos = list[l];
            if ((pos >> 9) == b && heads[pos] == s1) {
                val += (tanhf(u[(size_t)l * DD + o] + bco) - t_off) * Wr[pos & 511];
            }
        }
        out[(size_t)row * DD + o] = val;
    }
}

// ---------------------------------------------------------------------------
extern "C" void kernel_launch(void* const* d_in, const int* in_sizes, int n_in,
                              void* d_out, int out_size, void* d_ws, size_t ws_size,
                              hipStream_t stream) {
    const int* tokens = (const int*)d_in[0];
    // d_in[1] = dep_types: computed-but-discarded in the reference (bug preserved)
    const int* heads = (const int*)d_in[2];
    const float* tok_table = (const float*)d_in[3];
    const float* Wc = (const float*)d_in[4];
    const float* bc = (const float*)d_in[5];
    const float* Wr = (const float*)d_in[6];
    const float* br = (const float*)d_in[7];
    float* out = (float*)d_out;

    char* ws = (char*)d_ws;
    int* countp = (int*)ws;
    int* list = (int*)(ws + WS_LIST_OFF);
    float* u = (float*)(ws + WS_U_OFF);

    long maxl_l = ((long)ws_size - WS_U_OFF) / (DD * 4);
    int maxl = maxl_l < 0 ? 0 : (maxl_l > MAXL_CAP ? MAXL_CAP : (int)maxl_l);

    // zero count + list + u scratch (harness poisons ws with 0xAA every call)
    hipMemsetAsync(d_ws, 0, (size_t)WS_U_OFF + (size_t)maxl * DD * 4, stream);

    flag_kernel<<<BB, SS, 0, stream>>>(heads, countp, list, maxl);
    bilinear_kernel<<<dim3(DD / OT, KCH), NT, 0, stream>>>(
        Wc, tok_table, tokens, list, countp, u, maxl);
    finalize_kernel<<<BB * SS, 128, 0, stream>>>(
        heads, Wr, bc, br, list, countp, u, out, maxl);
}